// Round 7
// baseline (274.827 us; speedup 1.0000x reference)
//
#include <hip/hip_runtime.h>
#include <hip/hip_bf16.h>

// Problem constants (from reference setup_inputs)
constexpr int B_ = 2, T_ = 4096, D_ = 1024, H_ = 8, HD_ = 128, L_ = 5;
constexpr int M_ = B_ * T_;   // 8192 GEMM rows
constexpr int K_ = D_;        // 1024
constexpr int N_ = D_;        // 1024
constexpr int TB_ = 64;       // attention: t-rows per block
constexpr int NSMAX_ = 96;    // attention: max strip rows (supports dil<=8)

typedef __attribute__((ext_vector_type(8))) __bf16 bf16x8;
typedef __attribute__((ext_vector_type(4))) float f32x4;

__device__ __constant__ int c_srck[8]  = {0, 1, 2, 3, 4, 5, 6, 6};
__device__ __constant__ int c_shift[8] = {0, 0, 0, 0, -2, -1, 1, 2};

// ---------------------------------------------------------------------------
// Fused-convert GEMM v2 (reg-staged): y = x @ W^T + b, f32 inputs, bf16 MFMA.
//
// Unlike R5's refuted f32-LDS variant, this stages global f32 -> REGISTERS ->
// RNE-convert -> ds_write_b128 into the SAME 8KB bf16 LDS layout as the
// proven 71.7us bf16 kernel. So: LDS bytes, fragment ds_reads, MFMA order,
// and numerics are bit-identical to the cvt_kernel+bf16-GEMM path (absmax
// 0.015625), while the 51.5us cvt dispatch and one launch gap disappear.
// T14 issue-early/write-late: tile k+1's 8 float4 loads are issued right
// after the post-write barrier of tile k, hiding HBM/L2 latency under the
// fragment reads + 16 MFMA of tile k.
// z = 0/1/2 selects (query,Wq,bq)/(key,Wk,bk)/(value,Wv,bv).
// ---------------------------------------------------------------------------
__global__ __launch_bounds__(256) void qkv_gemm_fused(
    const float* __restrict__ query,
    const float* __restrict__ key,
    const float* __restrict__ value,
    const float* __restrict__ Wq,
    const float* __restrict__ bq,
    const float* __restrict__ Wk,
    const float* __restrict__ bk,
    const float* __restrict__ Wv,
    const float* __restrict__ bv,
    __hip_bfloat16* __restrict__ qout,
    __hip_bfloat16* __restrict__ kout,
    __hip_bfloat16* __restrict__ vout)
{
    const int z = blockIdx.z;
    const float* A    = (z == 0) ? query : (z == 1) ? key : value;
    const float* W    = (z == 0) ? Wq    : (z == 1) ? Wk  : Wv;
    const float* bias = (z == 0) ? bq    : (z == 1) ? bk  : bv;
    __hip_bfloat16* C = (z == 0) ? qout  : (z == 1) ? kout : vout;

    __shared__ __align__(16) __hip_bfloat16 As[128 * 32];   // 8 KB (bf16!)
    __shared__ __align__(16) __hip_bfloat16 Bs[128 * 32];   // 8 KB

    const int tid  = threadIdx.x;
    const int wave = tid >> 6;
    const int lane = tid & 63;
    const int m0 = blockIdx.x * 128;
    const int n0 = blockIdx.y * 128;
    const int wm = (wave >> 1) * 64;
    const int wn = (wave & 1) * 64;

    f32x4 acc[4][4];
#pragma unroll
    for (int i = 0; i < 4; ++i)
#pragma unroll
        for (int j = 0; j < 4; ++j)
            acc[i][j] = (f32x4){0.f, 0.f, 0.f, 0.f};

    // staging geometry — identical LDS destination map to the proven bf16
    // kernel's global_load_lds: issue i = wave + r*4 covers rows
    // [i*16, i*16+16); lane -> row i*16 + lane/4, f32 cols (lane&3)*8..+7;
    // LDS dst = As + issue*512 + lane*8 (bf16 elems, 16B per lane).
    const int srow = lane >> 2;
    const int scol = (lane & 3) * 8;

    const int fr = lane & 15;          // fragment row
    const int fk = (lane >> 4) * 8;    // fragment k offset (16B aligned)

    // single reg buffer for the in-flight tile: 8 x f32x4 (32 VGPR)
    f32x4 rA[2][2], rW[2][2];

    auto loadRegs = [&](int k0) {
#pragma unroll
        for (int r = 0; r < 2; ++r) {
            const int row = (wave + r * 4) * 16 + srow;
            const float* pa = A + (size_t)(m0 + row) * K_ + k0 + scol;
            const float* pw = W + (size_t)(n0 + row) * K_ + k0 + scol;
            rA[r][0] = *(const f32x4*)(const void*)pa;
            rA[r][1] = *(const f32x4*)(const void*)(pa + 4);
            rW[r][0] = *(const f32x4*)(const void*)pw;
            rW[r][1] = *(const f32x4*)(const void*)(pw + 4);
        }
    };
    auto writeLds = [&]() {
#pragma unroll
        for (int r = 0; r < 2; ++r) {
            const int issue = wave + r * 4;
            bf16x8 oa, ow;
#pragma unroll
            for (int e = 0; e < 4; ++e) {
                oa[e]     = (__bf16)rA[r][0][e];
                oa[e + 4] = (__bf16)rA[r][1][e];
                ow[e]     = (__bf16)rW[r][0][e];
                ow[e + 4] = (__bf16)rW[r][1][e];
            }
            *(bf16x8*)(void*)(As + issue * 512 + lane * 8) = oa;
            *(bf16x8*)(void*)(Bs + issue * 512 + lane * 8) = ow;
        }
    };

    loadRegs(0);                       // prologue: tile 0 in flight

    for (int k0 = 0; k0 < K_; k0 += 32) {
        // convert + write tile k (implicit vmcnt wait on first reg use)
        writeLds();
        __syncthreads();               // writes visible to all waves

        // issue tile k+1 loads EARLY — latency hides under this tile's
        // fragment reads + 16 MFMA (regs are dead after writeLds; WAR-safe)
        if (k0 + 32 < K_) loadRegs(k0 + 32);

        bf16x8 af[4], bf[4];
#pragma unroll
        for (int i = 0; i < 4; ++i) {
            af[i] = *(const bf16x8*)(const void*)(As + (wm + i * 16 + fr) * 32 + fk);
            bf[i] = *(const bf16x8*)(const void*)(Bs + (wn + i * 16 + fr) * 32 + fk);
        }
#pragma unroll
        for (int i = 0; i < 4; ++i)
#pragma unroll
            for (int j = 0; j < 4; ++j)
                acc[i][j] = __builtin_amdgcn_mfma_f32_16x16x32_bf16(
                    af[i], bf[j], acc[i][j], 0, 0, 0);
        __syncthreads();               // reads done before next tile's writes
    }

    // epilogue: C/D layout col=lane&15, row=(lane>>4)*4+r (m89)
    const int col_l = lane & 15;
    const int row_l = (lane >> 4) * 4;
#pragma unroll
    for (int j = 0; j < 4; ++j) {
        const int n = n0 + wn + j * 16 + col_l;
        const float bval = bias[n];
#pragma unroll
        for (int i = 0; i < 4; ++i) {
            const int m = m0 + wm + i * 16 + row_l;
#pragma unroll
            for (int r = 0; r < 4; ++r)
                C[(size_t)(m + r) * N_ + n] = __float2bfloat16(acc[i][j][r] + bval);
        }
    }
}

// ---------------------------------------------------------------------------
// Attention v2 (unchanged, verified): one block per (b, h, 64-t strip).
// K/V strips staged in LDS (16B XOR swizzle), Er transposed in LDS.
// 4 lanes per row x 32 dims/lane. orig(t,j) = t + (shift+j-2)*dil, valid iff
// 0<=orig<T. OOB strip rows zero-filled (no NaN).
// ---------------------------------------------------------------------------
__global__ __launch_bounds__(256) void attn_kernel(
    const __hip_bfloat16* __restrict__ qp,
    const __hip_bfloat16* __restrict__ kp,
    const __hip_bfloat16* __restrict__ vp,
    const float* __restrict__ Er,
    const int* __restrict__ layer_p,
    float* __restrict__ out,
    float* __restrict__ attn_out)
{
    const int dil = 1 << (*layer_p);
    int NS = TB_ + 4 * dil;
    if (NS > NSMAX_) NS = NSMAX_;     // geometry beyond layer=3 unsupported

    const int tid = threadIdx.x;
    const int t0 = blockIdx.x * TB_;
    const int h  = blockIdx.y;
    const int b  = blockIdx.z;
    const int shift = c_shift[h];
    const int srck  = c_srck[h];
    const int off_lo = (shift - 2) * dil;

    __shared__ __align__(16) __hip_bfloat16 Ks[NSMAX_ * 128];  // 24 KB
    __shared__ __align__(16) __hip_bfloat16 Vs[NSMAX_ * 128];  // 24 KB
    __shared__ __align__(16) float ErT[5][128];                // 2.5 KB

    // stage ErT[j][d] = Er[h, d, j] (source contiguous, coalesced)
    for (int i = tid; i < 640; i += 256) {
        const int d = i / 5, j = i - d * 5;
        ErT[j][d] = Er[(size_t)h * 640 + i];
    }

    // stage K/V strips: 16 rows per pass, lane sc covers 16B chunk sc
    const int sr = tid >> 4;
    const int sc = tid & 15;
    for (int i0 = 0; i0 < NS; i0 += 16) {
        const int i = i0 + sr;
        if (i < NS) {
            const int r = t0 + off_lo + i;
            bf16x8 kv8 = (bf16x8){0, 0, 0, 0, 0, 0, 0, 0};
            bf16x8 vv8 = (bf16x8){0, 0, 0, 0, 0, 0, 0, 0};
            if (r >= 0 && r < T_) {
                kv8 = *(const bf16x8*)(const void*)(
                    kp + (size_t)(b * T_ + r) * D_ + srck * HD_ + sc * 8);
                vv8 = *(const bf16x8*)(const void*)(
                    vp + (size_t)(b * T_ + r) * D_ + h * HD_ + sc * 8);
            }
            const int pc = sc ^ (i & 3);
            *(bf16x8*)(void*)(Ks + i * 128 + pc * 8) = kv8;
            *(bf16x8*)(void*)(Vs + i * 128 + pc * 8) = vv8;
        }
    }
    __syncthreads();

    // compute: row t = t0 + tid/4; lane quarter ld = tid%4 owns dims ld*32..+31
    const int lr = tid >> 2;
    const int ld = tid & 3;
    const int t  = t0 + lr;
    const size_t qoff = (size_t)(b * T_ + t) * D_ + h * HD_ + ld * 32;

    float qf[32];
#pragma unroll
    for (int c = 0; c < 4; ++c) {
        bf16x8 qv = *(const bf16x8*)(const void*)(qp + qoff + c * 8);
#pragma unroll
        for (int e = 0; e < 8; ++e) qf[c * 8 + e] = (float)qv[e];
    }

    float lg[5];
    bool  valid[5];
    int   irow[5];
#pragma unroll
    for (int j = 0; j < 5; ++j) {
        const int i = lr + j * dil;          // strip row
        irow[j] = i;
        const int orig = t + (shift + j - 2) * dil;
        valid[j] = (orig >= 0) && (orig < T_);

        float s = 0.f;
#pragma unroll
        for (int c = 0; c < 4; ++c) {
            const int pc = (ld * 4 + c) ^ (i & 3);
            bf16x8 kk = *(const bf16x8*)(const void*)(Ks + i * 128 + pc * 8);
#pragma unroll
            for (int e = 0; e < 8; ++e) s += qf[c * 8 + e] * (float)kk[e];
        }
        if (!valid[j]) s = 0.f;              // mirror qk==0 masking base
#pragma unroll
        for (int c = 0; c < 8; ++c) {
            f32x4 ev = *(const f32x4*)(const void*)(&ErT[j][ld * 32 + c * 4]);
#pragma unroll
            for (int e = 0; e < 4; ++e) s += qf[c * 4 + e] * ev[e];
        }
        s += __shfl_xor(s, 1, 4);
        s += __shfl_xor(s, 2, 4);
        lg[j] = valid[j] ? s * 0.08838834764831845f : -INFINITY;
    }

    float mx = lg[0];
#pragma unroll
    for (int j = 1; j < 5; ++j) mx = fmaxf(mx, lg[j]);
    float w[5], sum = 0.f;
#pragma unroll
    for (int j = 0; j < 5; ++j) {
        w[j] = valid[j] ? __expf(lg[j] - mx) : 0.f;
        sum += w[j];
    }
    const float inv = 1.f / sum;
#pragma unroll
    for (int j = 0; j < 5; ++j) w[j] *= inv;

    float o[32];
#pragma unroll
    for (int m = 0; m < 32; ++m) o[m] = 0.f;
#pragma unroll
    for (int j = 0; j < 5; ++j) {
        const int i = irow[j];
#pragma unroll
        for (int c = 0; c < 4; ++c) {
            const int pc = (ld * 4 + c) ^ (i & 3);
            bf16x8 vv = *(const bf16x8*)(const void*)(Vs + i * 128 + pc * 8);
#pragma unroll
            for (int e = 0; e < 8; ++e) o[c * 8 + e] += w[j] * (float)vv[e];
        }
    }

#pragma unroll
    for (int c = 0; c < 8; ++c) {
        f32x4 ov = (f32x4){o[c * 4], o[c * 4 + 1], o[c * 4 + 2], o[c * 4 + 3]};
        *(f32x4*)(void*)(out + qoff + c * 4) = ov;
    }

    const size_t abase = ((size_t)(b * H_ + h) * T_ + t) * L_;
    attn_out[abase + ld] = w[ld];
    if (ld == 0) attn_out[abase + 4] = w[4];
}

// ---------------------------------------------------------------------------
extern "C" void kernel_launch(void* const* d_in, const int* in_sizes, int n_in,
                              void* d_out, int out_size, void* d_ws, size_t ws_size,
                              hipStream_t stream) {
    const float* query = (const float*)d_in[0];
    const float* key   = (const float*)d_in[1];
    const float* value = (const float*)d_in[2];
    const float* Wq    = (const float*)d_in[3];
    const float* bq    = (const float*)d_in[4];
    const float* Wk    = (const float*)d_in[5];
    const float* bk    = (const float*)d_in[6];
    const float* Wv    = (const float*)d_in[7];
    const float* bv    = (const float*)d_in[8];
    const float* Er    = (const float*)d_in[9];
    const int*   layer = (const int*)d_in[10];

    float* out  = (float*)d_out;
    float* attn = out + (size_t)B_ * T_ * D_;

    const size_t SP = (size_t)M_ * N_;       // 8M elems per projected tensor

    __hip_bfloat16* qp = (__hip_bfloat16*)d_ws;
    __hip_bfloat16* kp = qp + SP;
    __hip_bfloat16* vp = kp + SP;

    // two dispatches total: fused convert+project, then attention
    qkv_gemm_fused<<<dim3(M_ / 128, N_ / 128, 3), 256, 0, stream>>>(
        query, key, value, Wq, bq, Wk, bk, Wv, bv, qp, kp, vp);

    attn_kernel<<<dim3(T_ / TB_, H_, B_), 256, 0, stream>>>(
        qp, kp, vp, Er, layer, out, attn);
}

// Round 8
// 251.564 us; speedup vs baseline: 1.0925x; 1.0925x over previous
//
#include <hip/hip_runtime.h>
#include <hip/hip_bf16.h>

// Problem constants (from reference setup_inputs)
constexpr int B_ = 2, T_ = 4096, D_ = 1024, H_ = 8, HD_ = 128, L_ = 5;
constexpr int M_ = B_ * T_;   // 8192 GEMM rows
constexpr int K_ = D_;        // 1024
constexpr int N_ = D_;        // 1024
constexpr int TB_ = 64;       // attention: t-rows per block
constexpr int NSMAX_ = 96;    // attention: max strip rows (supports dil<=8)

typedef __attribute__((ext_vector_type(8))) __bf16 bf16x8;
typedef __attribute__((ext_vector_type(4))) float f32x4;

__device__ __constant__ int c_srck[8]  = {0, 1, 2, 3, 4, 5, 6, 6};
__device__ __constant__ int c_shift[8] = {0, 0, 0, 0, -2, -1, 1, 2};

__device__ __forceinline__ void gload_lds16(const void* g, void* l) {
    __builtin_amdgcn_global_load_lds(
        (__attribute__((address_space(1))) void*)g,
        (__attribute__((address_space(3))) void*)l, 16, 0, 0);
}

// ---------------------------------------------------------------------------
// f32 -> bf16 bulk convert (R0-proven, 51.5us): grid.y selects q/k/v set.
// blockIdx.x < 4096 -> input tensor (8M elems); else weight (1M elems).
// NOTE: fusing this into the GEMM is REFUTED twice (R5 f32-LDS: 137us,
// R7 reg-staged: 135us) — f32 panel re-reads overflow L3 (FETCH 57->99MB).
// The pre-convert halves the re-read footprint so it L3-fits.
// ---------------------------------------------------------------------------
__global__ __launch_bounds__(256) void cvt_kernel(
    const float* __restrict__ q,  const float* __restrict__ k,  const float* __restrict__ v,
    const float* __restrict__ wq, const float* __restrict__ wk, const float* __restrict__ wv,
    __hip_bfloat16* __restrict__ qb,  __hip_bfloat16* __restrict__ kb,  __hip_bfloat16* __restrict__ vb,
    __hip_bfloat16* __restrict__ wqb, __hip_bfloat16* __restrict__ wkb, __hip_bfloat16* __restrict__ wvb)
{
    const int y = blockIdx.y;
    const float* src;
    __hip_bfloat16* dst;
    size_t idx;
    if (blockIdx.x < 4096) {
        src = (y == 0) ? q : (y == 1) ? k : v;
        dst = (y == 0) ? qb : (y == 1) ? kb : vb;
        idx = ((size_t)blockIdx.x * 256 + threadIdx.x) * 8;
    } else {
        src = (y == 0) ? wq : (y == 1) ? wk : wv;
        dst = (y == 0) ? wqb : (y == 1) ? wkb : wvb;
        idx = ((size_t)(blockIdx.x - 4096) * 256 + threadIdx.x) * 8;
    }
    f32x4 a = *(const f32x4*)(const void*)(src + idx);
    f32x4 b = *(const f32x4*)(const void*)(src + idx + 4);
    bf16x8 o;
#pragma unroll
    for (int e = 0; e < 4; ++e) { o[e] = (__bf16)a[e]; o[e + 4] = (__bf16)b[e]; }
    *(bf16x8*)(void*)(dst + idx) = o;
}

// ---------------------------------------------------------------------------
// Fast GEMM (R0-proven 2-phase m97 structure, 71.7us): y = x @ W^T + b.
// x: [M,K] bf16 row-major, W: [N,K] bf16 row-major, bias f32, C bf16.
// Single z=3 dispatch (launch gaps ~6.5us each; fewer dispatches win).
// 8-phase 256^2 port refuted twice (R1: 85us, R3: 77us w/ derived waits).
// ---------------------------------------------------------------------------
__global__ __launch_bounds__(256) void qkv_gemm_bf16(
    const __hip_bfloat16* __restrict__ qb,
    const __hip_bfloat16* __restrict__ kb,
    const __hip_bfloat16* __restrict__ vb,
    const __hip_bfloat16* __restrict__ wqb,
    const __hip_bfloat16* __restrict__ wkb,
    const __hip_bfloat16* __restrict__ wvb,
    const float* __restrict__ bq,
    const float* __restrict__ bk,
    const float* __restrict__ bv,
    __hip_bfloat16* __restrict__ qout,
    __hip_bfloat16* __restrict__ kout,
    __hip_bfloat16* __restrict__ vout)
{
    const int z = blockIdx.z;
    const __hip_bfloat16* A = (z == 0) ? qb  : (z == 1) ? kb  : vb;
    const __hip_bfloat16* W = (z == 0) ? wqb : (z == 1) ? wkb : wvb;
    const float* bias       = (z == 0) ? bq  : (z == 1) ? bk  : bv;
    __hip_bfloat16* C       = (z == 0) ? qout : (z == 1) ? kout : vout;

    __shared__ __align__(16) __hip_bfloat16 As[128 * 32];   // 8 KB
    __shared__ __align__(16) __hip_bfloat16 Bs[128 * 32];   // 8 KB

    const int tid  = threadIdx.x;
    const int wave = tid >> 6;
    const int lane = tid & 63;
    const int m0 = blockIdx.x * 128;
    const int n0 = blockIdx.y * 128;
    const int wm = (wave >> 1) * 64;
    const int wn = (wave & 1) * 64;

    f32x4 acc[4][4];
#pragma unroll
    for (int i = 0; i < 4; ++i)
#pragma unroll
        for (int j = 0; j < 4; ++j)
            acc[i][j] = (f32x4){0.f, 0.f, 0.f, 0.f};

    // staging: issue i (0..7) covers rows [i*16, i*16+16), lane -> row i*16+l/4,
    // col (l%4)*8 (16B); LDS dst = As + i*512 elems + lane*8 (contiguous).
    const int srow = lane >> 2;
    const int scol = (lane & 3) * 8;

    const int fr = lane & 15;          // fragment row
    const int fk = (lane >> 4) * 8;    // fragment k offset (16B aligned)

    for (int k0 = 0; k0 < K_; k0 += 32) {
#pragma unroll
        for (int r = 0; r < 2; ++r) {
            const int issue = wave + r * 4;        // 0..7
            const int row = issue * 16 + srow;
            gload_lds16(A + (size_t)(m0 + row) * K_ + k0 + scol,
                        (void*)(As + issue * 512));
            gload_lds16(W + (size_t)(n0 + row) * K_ + k0 + scol,
                        (void*)(Bs + issue * 512));
        }
        __syncthreads();

        bf16x8 af[4], bf[4];
#pragma unroll
        for (int i = 0; i < 4; ++i) {
            af[i] = *(const bf16x8*)(const void*)(As + (wm + i * 16 + fr) * 32 + fk);
            bf[i] = *(const bf16x8*)(const void*)(Bs + (wn + i * 16 + fr) * 32 + fk);
        }
#pragma unroll
        for (int i = 0; i < 4; ++i)
#pragma unroll
            for (int j = 0; j < 4; ++j)
                acc[i][j] = __builtin_amdgcn_mfma_f32_16x16x32_bf16(
                    af[i], bf[j], acc[i][j], 0, 0, 0);
        __syncthreads();
    }

    const int col_l = lane & 15;
    const int row_l = (lane >> 4) * 4;
#pragma unroll
    for (int j = 0; j < 4; ++j) {
        const int n = n0 + wn + j * 16 + col_l;
        const float bval = bias[n];
#pragma unroll
        for (int i = 0; i < 4; ++i) {
            const int m = m0 + wm + i * 16 + row_l;
#pragma unroll
            for (int r = 0; r < 4; ++r)
                C[(size_t)(m + r) * N_ + n] = __float2bfloat16(acc[i][j][r] + bval);
        }
    }
}

// ---------------------------------------------------------------------------
// Fallback GEMM: f32 staging with XOR swizzle. Used only if ws_size is too
// small for the bf16 pre-convert buffers.
// ---------------------------------------------------------------------------
__global__ __launch_bounds__(256) void qkv_gemm_f32(
    const float* __restrict__ query,
    const float* __restrict__ key,
    const float* __restrict__ value,
    const float* __restrict__ Wq,
    const float* __restrict__ bq,
    const float* __restrict__ Wk,
    const float* __restrict__ bk,
    const float* __restrict__ Wv,
    const float* __restrict__ bv,
    __hip_bfloat16* __restrict__ qout,
    __hip_bfloat16* __restrict__ kout,
    __hip_bfloat16* __restrict__ vout)
{
    const int z = blockIdx.z;
    const float* A    = (z == 0) ? query : (z == 1) ? key : value;
    const float* W    = (z == 0) ? Wq    : (z == 1) ? Wk  : Wv;
    const float* bias = (z == 0) ? bq    : (z == 1) ? bk  : bv;
    __hip_bfloat16* C = (z == 0) ? qout  : (z == 1) ? kout : vout;

    __shared__ __align__(16) float As[128 * 32];
    __shared__ __align__(16) float Bs[128 * 32];

    const int tid  = threadIdx.x;
    const int wave = tid >> 6;
    const int lane = tid & 63;
    const int m0 = blockIdx.x * 128;
    const int n0 = blockIdx.y * 128;
    const int wm = (wave >> 1) * 64;
    const int wn = (wave & 1) * 64;

    f32x4 acc[4][4];
#pragma unroll
    for (int i = 0; i < 4; ++i)
#pragma unroll
        for (int j = 0; j < 4; ++j)
            acc[i][j] = (f32x4){0.f, 0.f, 0.f, 0.f};

    const int srow = lane >> 3;
    const int lcg  = (lane & 7) ^ srow;
    const int gcol = lcg * 4;

    const int fr  = lane & 15;
    const int r7  = fr & 7;
    const int cgA = (lane >> 4) * 2;
    const int pcg0 = (cgA)     ^ r7;
    const int pcg1 = (cgA ^ 1) ^ r7;

    for (int k0 = 0; k0 < K_; k0 += 32) {
#pragma unroll
        for (int r = 0; r < 4; ++r) {
            const int issue = wave + r * 4;
            const int row = issue * 8 + srow;
            gload_lds16(A + (size_t)(m0 + row) * K_ + k0 + gcol,
                        (void*)(As + issue * 256));
            gload_lds16(W + (size_t)(n0 + row) * K_ + k0 + gcol,
                        (void*)(Bs + issue * 256));
        }
        __syncthreads();

        bf16x8 af[4], bf[4];
#pragma unroll
        for (int i = 0; i < 4; ++i) {
            const float* ap = As + (wm + i * 16 + fr) * 32;
            f32x4 a0 = *(const f32x4*)(const void*)(ap + pcg0 * 4);
            f32x4 a1 = *(const f32x4*)(const void*)(ap + pcg1 * 4);
            const float* bp = Bs + (wn + i * 16 + fr) * 32;
            f32x4 b0 = *(const f32x4*)(const void*)(bp + pcg0 * 4);
            f32x4 b1 = *(const f32x4*)(const void*)(bp + pcg1 * 4);
#pragma unroll
            for (int e = 0; e < 4; ++e) {
                af[i][e]     = (__bf16)a0[e];
                af[i][e + 4] = (__bf16)a1[e];
                bf[i][e]     = (__bf16)b0[e];
                bf[i][e + 4] = (__bf16)b1[e];
            }
        }
#pragma unroll
        for (int i = 0; i < 4; ++i)
#pragma unroll
            for (int j = 0; j < 4; ++j)
                acc[i][j] = __builtin_amdgcn_mfma_f32_16x16x32_bf16(
                    af[i], bf[j], acc[i][j], 0, 0, 0);
        __syncthreads();
    }

    const int col_l = lane & 15;
    const int row_l = (lane >> 4) * 4;
#pragma unroll
    for (int j = 0; j < 4; ++j) {
        const int n = n0 + wn + j * 16 + col_l;
        const float bval = bias[n];
#pragma unroll
        for (int i = 0; i < 4; ++i) {
            const int m = m0 + wm + i * 16 + row_l;
#pragma unroll
            for (int r = 0; r < 4; ++r)
                C[(size_t)(m + r) * N_ + n] = __float2bfloat16(acc[i][j][r] + bval);
        }
    }
}

// ---------------------------------------------------------------------------
// Attention v3: V is NOT staged in LDS (Common-mistake #7 / m169: V rows
// have 20x in-block reuse with full L1/L2 locality -> staging was pure
// overhead). LDS drops 50.6 -> 26.6 KB => 6 blocks/CU (was 3), removing
// the scheduling tail at 1024 blocks (4 blocks/CU of work). V global row
// index == orig (= t + (shift+j-2)*dil) and invalid j's have w[j]=0, so
// guarded direct reads are bit-identical to the zero-filled LDS path.
// K stays LDS-staged (QK dot is the latency-sensitive chain).
// ---------------------------------------------------------------------------
__global__ __launch_bounds__(256) void attn_kernel(
    const __hip_bfloat16* __restrict__ qp,
    const __hip_bfloat16* __restrict__ kp,
    const __hip_bfloat16* __restrict__ vp,
    const float* __restrict__ Er,
    const int* __restrict__ layer_p,
    float* __restrict__ out,
    float* __restrict__ attn_out)
{
    const int dil = 1 << (*layer_p);
    int NS = TB_ + 4 * dil;
    if (NS > NSMAX_) NS = NSMAX_;     // geometry beyond layer=3 unsupported

    const int tid = threadIdx.x;
    const int t0 = blockIdx.x * TB_;
    const int h  = blockIdx.y;
    const int b  = blockIdx.z;
    const int shift = c_shift[h];
    const int srck  = c_srck[h];
    const int off_lo = (shift - 2) * dil;

    __shared__ __align__(16) __hip_bfloat16 Ks[NSMAX_ * 128];  // 24 KB
    __shared__ __align__(16) float ErT[5][128];                // 2.5 KB

    // stage ErT[j][d] = Er[h, d, j] (source contiguous, coalesced)
    for (int i = tid; i < 640; i += 256) {
        const int d = i / 5, j = i - d * 5;
        ErT[j][d] = Er[(size_t)h * 640 + i];
    }

    // stage K strip: 16 rows per pass, lane sc covers 16B chunk sc
    const int sr = tid >> 4;
    const int sc = tid & 15;
    for (int i0 = 0; i0 < NS; i0 += 16) {
        const int i = i0 + sr;
        if (i < NS) {
            const int r = t0 + off_lo + i;
            bf16x8 kv8 = (bf16x8){0, 0, 0, 0, 0, 0, 0, 0};
            if (r >= 0 && r < T_) {
                kv8 = *(const bf16x8*)(const void*)(
                    kp + (size_t)(b * T_ + r) * D_ + srck * HD_ + sc * 8);
            }
            const int pc = sc ^ (i & 3);
            *(bf16x8*)(void*)(Ks + i * 128 + pc * 8) = kv8;
        }
    }

    // Q load hoisted above the barrier (independent of LDS) — overlaps staging
    const int lr = tid >> 2;
    const int ld = tid & 3;
    const int t  = t0 + lr;
    const size_t qoff = (size_t)(b * T_ + t) * D_ + h * HD_ + ld * 32;

    float qf[32];
#pragma unroll
    for (int c = 0; c < 4; ++c) {
        bf16x8 qv = *(const bf16x8*)(const void*)(qp + qoff + c * 8);
#pragma unroll
        for (int e = 0; e < 8; ++e) qf[c * 8 + e] = (float)qv[e];
    }
    __syncthreads();

    float lg[5];
    bool  valid[5];
    int   orig[5];
#pragma unroll
    for (int j = 0; j < 5; ++j) {
        const int i = lr + j * dil;          // strip row
        orig[j] = t + (shift + j - 2) * dil; // == t0 + off_lo + i
        valid[j] = (orig[j] >= 0) && (orig[j] < T_);

        float s = 0.f;
#pragma unroll
        for (int c = 0; c < 4; ++c) {
            const int pc = (ld * 4 + c) ^ (i & 3);
            bf16x8 kk = *(const bf16x8*)(const void*)(Ks + i * 128 + pc * 8);
#pragma unroll
            for (int e = 0; e < 8; ++e) s += qf[c * 8 + e] * (float)kk[e];
        }
        if (!valid[j]) s = 0.f;              // mirror qk==0 masking base
#pragma unroll
        for (int c = 0; c < 8; ++c) {
            f32x4 ev = *(const f32x4*)(const void*)(&ErT[j][ld * 32 + c * 4]);
#pragma unroll
            for (int e = 0; e < 4; ++e) s += qf[c * 4 + e] * ev[e];
        }
        s += __shfl_xor(s, 1, 4);
        s += __shfl_xor(s, 2, 4);
        lg[j] = valid[j] ? s * 0.08838834764831845f : -INFINITY;
    }

    float mx = lg[0];
#pragma unroll
    for (int j = 1; j < 5; ++j) mx = fmaxf(mx, lg[j]);
    float w[5], sum = 0.f;
#pragma unroll
    for (int j = 0; j < 5; ++j) {
        w[j] = valid[j] ? __expf(lg[j] - mx) : 0.f;
        sum += w[j];
    }
    const float inv = 1.f / sum;
#pragma unroll
    for (int j = 0; j < 5; ++j) w[j] *= inv;

    // PV: direct global V reads (guarded — w[j]==0 for invalid j anyway)
    float o[32];
#pragma unroll
    for (int m = 0; m < 32; ++m) o[m] = 0.f;
#pragma unroll
    for (int j = 0; j < 5; ++j) {
        if (valid[j]) {
            const __hip_bfloat16* vrow =
                vp + (size_t)(b * T_ + orig[j]) * D_ + h * HD_ + ld * 32;
#pragma unroll
            for (int c = 0; c < 4; ++c) {
                bf16x8 vv = *(const bf16x8*)(const void*)(vrow + c * 8);
#pragma unroll
                for (int e = 0; e < 8; ++e) o[c * 8 + e] += w[j] * (float)vv[e];
            }
        }
    }

#pragma unroll
    for (int c = 0; c < 8; ++c) {
        f32x4 ov = (f32x4){o[c * 4], o[c * 4 + 1], o[c * 4 + 2], o[c * 4 + 3]};
        *(f32x4*)(void*)(out + qoff + c * 4) = ov;
    }

    const size_t abase = ((size_t)(b * H_ + h) * T_ + t) * L_;
    attn_out[abase + ld] = w[ld];
    if (ld == 0) attn_out[abase + 4] = w[4];
}

// ---------------------------------------------------------------------------
extern "C" void kernel_launch(void* const* d_in, const int* in_sizes, int n_in,
                              void* d_out, int out_size, void* d_ws, size_t ws_size,
                              hipStream_t stream) {
    const float* query = (const float*)d_in[0];
    const float* key   = (const float*)d_in[1];
    const float* value = (const float*)d_in[2];
    const float* Wq    = (const float*)d_in[3];
    const float* bq    = (const float*)d_in[4];
    const float* Wk    = (const float*)d_in[5];
    const float* bk    = (const float*)d_in[6];
    const float* Wv    = (const float*)d_in[7];
    const float* bv    = (const float*)d_in[8];
    const float* Er    = (const float*)d_in[9];
    const int*   layer = (const int*)d_in[10];

    float* out  = (float*)d_out;
    float* attn = out + (size_t)B_ * T_ * D_;

    const size_t SA = (size_t)M_ * K_;       // 8M elems
    const size_t SW = (size_t)N_ * K_;       // 1M elems
    const size_t SP = (size_t)M_ * N_;       // 8M elems
    const size_t need = (3 * SA + 3 * SW + 3 * SP) * sizeof(__hip_bfloat16);

    char* ws = (char*)d_ws;
    if (ws_size >= need) {
        __hip_bfloat16* qb  = (__hip_bfloat16*)ws;
        __hip_bfloat16* kb  = qb + SA;
        __hip_bfloat16* vb  = kb + SA;
        __hip_bfloat16* wqb = vb + SA;
        __hip_bfloat16* wkb = wqb + SW;
        __hip_bfloat16* wvb = wkb + SW;
        __hip_bfloat16* qp  = wvb + SW;
        __hip_bfloat16* kp  = qp + SP;
        __hip_bfloat16* vp  = kp + SP;

        cvt_kernel<<<dim3(4608, 3), 256, 0, stream>>>(
            query, key, value, Wq, Wk, Wv, qb, kb, vb, wqb, wkb, wvb);

        qkv_gemm_bf16<<<dim3(M_ / 128, N_ / 128, 3), 256, 0, stream>>>(
            qb, kb, vb, wqb, wkb, wvb, bq, bk, bv, qp, kp, vp);

        attn_kernel<<<dim3(T_ / TB_, H_, B_), 256, 0, stream>>>(
            qp, kp, vp, Er, layer, out, attn);
    } else {
        __hip_bfloat16* qp = (__hip_bfloat16*)ws;
        __hip_bfloat16* kp = qp + SP;
        __hip_bfloat16* vp = kp + SP;

        qkv_gemm_f32<<<dim3(M_ / 128, N_ / 128, 3), 256, 0, stream>>>(
            query, key, value, Wq, bq, Wk, bk, Wv, bv, qp, kp, vp);

        attn_kernel<<<dim3(T_ / TB_, H_, B_), 256, 0, stream>>>(
            qp, kp, vp, Er, layer, out, attn);
    }
}